// Round 4
// baseline (586.506 us; speedup 1.0000x reference)
//
#include <hip/hip_runtime.h>

// RecursiveEncoder on MI355X. B=16, H=256, S=16, C=5, L=6, N_LEAF=15625, N_INT=3906.
// R4: level_kernel -> BARRIER-FREE direct-global register MFMA (AITER-style
//     MFMA<->VMEM interleave with vmcnt(N), no LDS, no __syncthreads). R3's
//     2-barrier lds-DMA loop was latency-bound (~30us per small level, l5 85us
//     at MfmaUtil 15%). B is L2-resident (0.65MB/type); A read 2x absorbed by L2.

#define B_ 16
#define H_ 256
#define NLEAF 15625
#define NINT 3906

typedef __bf16 bf16_t;
typedef bf16_t bf16x8 __attribute__((ext_vector_type(8)));
typedef bf16_t bf16x4 __attribute__((ext_vector_type(4)));
typedef float f32x4 __attribute__((ext_vector_type(4)));

// grid(24): t(3) x k-chunk(8 of 160). Reads coalesced (lane=h), writes 16B runs.
__global__ __launch_bounds__(256) void prep_kernel(const float* __restrict__ W_node,
                                                   bf16_t* __restrict__ Wt,
                                                   int* __restrict__ counters) {
  if (blockIdx.x == 0 && threadIdx.x < 18) counters[threadIdx.x] = 0;
  const int t = blockIdx.x / 8;
  const int kc = blockIdx.x % 8;
  const int h = threadIdx.x;
  const float* srcp = W_node + (size_t)t * 1280 * 256 + h;
  bf16_t* dstp = Wt + ((size_t)(t * 256 + h)) * 1280;
  for (int k0 = kc * 160; k0 < kc * 160 + 160; k0 += 8) {
    bf16x8 v;
#pragma unroll
    for (int j = 0; j < 8; ++j) v[j] = (bf16_t)srcp[(size_t)(k0 + j) * 256];
    *(bf16x8*)(dstp + k0) = v;
  }
}

// One row per wave, lane covers h = lane*4..lane*4+3; bf16x4 (8B) stores.
__global__ __launch_bounds__(256) void leaf_kernel(
    const float* __restrict__ leaf_box, const float* __restrict__ leaf_sem,
    const float* __restrict__ W_box, const float* __restrict__ b_box,
    const float* __restrict__ W_sem, const float* __restrict__ b_sem,
    bf16_t* __restrict__ f6) {
  const int lane = threadIdx.x & 63;
  const int wave = threadIdx.x >> 6;
  const int h0 = lane * 4;
  float wb[4][4], ws[16][4], bb[4], bs[4];
#pragma unroll
  for (int j = 0; j < 4; ++j) {
    float4 v = *(const float4*)(W_box + j * H_ + h0);
    wb[j][0] = v.x; wb[j][1] = v.y; wb[j][2] = v.z; wb[j][3] = v.w;
  }
#pragma unroll
  for (int j = 0; j < 16; ++j) {
    float4 v = *(const float4*)(W_sem + j * H_ + h0);
    ws[j][0] = v.x; ws[j][1] = v.y; ws[j][2] = v.z; ws[j][3] = v.w;
  }
  {
    float4 v = *(const float4*)(b_box + h0);
    bb[0] = v.x; bb[1] = v.y; bb[2] = v.z; bb[3] = v.w;
    float4 u = *(const float4*)(b_sem + h0);
    bs[0] = u.x; bs[1] = u.y; bs[2] = u.z; bs[3] = u.w;
  }
  const int ROWS = B_ * NLEAF;
  const int stride = gridDim.x * 4;
  for (int row = blockIdx.x * 4 + wave; row < ROWS; row += stride) {
    float4 bx = *(const float4*)(leaf_box + (size_t)row * 4);
    const float4* sp = (const float4*)(leaf_sem + (size_t)row * 16);
    float4 sv0 = sp[0], sv1 = sp[1], sv2 = sp[2], sv3 = sp[3];
    bf16x4 o;
#pragma unroll
    for (int c = 0; c < 4; ++c) {
      float s1 = fmaf(wb[0][c], bx.x, fmaf(wb[1][c], bx.y,
                 fmaf(wb[2][c], bx.z, fmaf(wb[3][c], bx.w, bb[c]))));
      float s2 = bs[c];
      s2 = fmaf(ws[0][c], sv0.x, s2);  s2 = fmaf(ws[1][c], sv0.y, s2);
      s2 = fmaf(ws[2][c], sv0.z, s2);  s2 = fmaf(ws[3][c], sv0.w, s2);
      s2 = fmaf(ws[4][c], sv1.x, s2);  s2 = fmaf(ws[5][c], sv1.y, s2);
      s2 = fmaf(ws[6][c], sv1.z, s2);  s2 = fmaf(ws[7][c], sv1.w, s2);
      s2 = fmaf(ws[8][c], sv2.x, s2);  s2 = fmaf(ws[9][c], sv2.y, s2);
      s2 = fmaf(ws[10][c], sv2.z, s2); s2 = fmaf(ws[11][c], sv2.w, s2);
      s2 = fmaf(ws[12][c], sv3.x, s2); s2 = fmaf(ws[13][c], sv3.y, s2);
      s2 = fmaf(ws[14][c], sv3.z, s2); s2 = fmaf(ws[15][c], sv3.w, s2);
      o[c] = (bf16_t)(fmaxf(s1, 0.f) + fmaxf(s2, 0.f));
    }
    *(bf16x4*)(f6 + (size_t)row * H_ + h0) = o;
  }
}

// LDS-aggregated bucketing.
__global__ __launch_bounds__(256) void bucket_kernel(const int* __restrict__ node_type,
                                                     int* __restrict__ counters,
                                                     int2* __restrict__ buckets) {
  __shared__ int lcnt[18];
  __shared__ int lbase[18];
  const int tid = threadIdx.x;
  if (tid < 18) lcnt[tid] = 0;
  __syncthreads();

  int idx = blockIdx.x * 256 + tid;
  bool active = idx < B_ * NINT;
  int t = 0, key = 0, mypos = 0;
  int2 e;
  int base = 0, nl_cap = 0;
  if (active) {
    int b = idx / NINT;
    int j = idx - b * NINT;
    int l, off;
    if (j >= 781)      { l = 5; off = 781; }
    else if (j >= 156) { l = 4; off = 156; }
    else if (j >= 31)  { l = 3; off = 31; }
    else if (j >= 6)   { l = 2; off = 6; }
    else if (j >= 1)   { l = 1; off = 1; }
    else               { l = 0; off = 0; }
    const int n_tab[6]    = {1, 5, 25, 125, 625, 3125};
    const int nn_tab[6]   = {5, 25, 125, 625, 3125, 15625};
    const int base_tab[6] = {0, 48, 288, 1488, 7488, 37488};
    int n_l = n_tab[l], nn = nn_tab[l];
    t = node_type[idx];
    int i = j - off;
    e.x = b * n_l + i;
    e.y = b * nn + 5 * i;
    base = base_tab[l];
    nl_cap = B_ * n_l;
    key = l * 3 + t;
    mypos = atomicAdd(&lcnt[key], 1);
  }
  __syncthreads();
  if (tid < 18) {
    int c = lcnt[tid];
    lbase[tid] = c ? atomicAdd(&counters[tid], c) : 0;
  }
  __syncthreads();
  if (active) {
    buckets[base + t * nl_cap + lbase[key] + mypos] = e;
  }
}

// 128x128 tile, K=1280 in 40 steps of 32. NO LDS, NO barriers: fragments loaded
// directly global->VGPR (b128), register double-buffered; compiler interleaves
// MFMA with loads via s_waitcnt vmcnt(8).
__global__ __launch_bounds__(256) void level_kernel(
    const bf16_t* __restrict__ src, bf16_t* __restrict__ dst,
    const int2* __restrict__ bucket, const int* __restrict__ counters,
    const bf16_t* __restrict__ Wt, const float* __restrict__ b_node,
    const float* __restrict__ ibox, const float* __restrict__ W_box,
    const float* __restrict__ b_box, int n_l, int off_l, int cap) {
  const int t = blockIdx.y;
  const int cnt = counters[t];
  const int tile0 = blockIdx.x * 128;
  if (tile0 >= cnt) return;
  const int nblk = blockIdx.z;
  const int2* rd = bucket + (size_t)t * cap;

  const int tid = threadIdx.x;
  const int lane = tid & 63;
  const int wave = tid >> 6;
  const int wm = wave & 1, wn = wave >> 1;
  const int quad = lane >> 4;
  const int l15 = lane & 15;

  // Per-lane fragment base pointers.
  // A frag for mfma_16x16x32: A[m=l15][k=quad*8+j] -> row (tile0+wm*64+am*16+l15), k-chunk quad*8
  const bf16_t* a_base[4];
#pragma unroll
  for (int am = 0; am < 4; ++am) {
    int gidx = tile0 + wm * 64 + am * 16 + l15;
    if (gidx >= cnt) gidx = cnt - 1;
    a_base[am] = src + (size_t)rd[gidx].y * H_ + quad * 8;
  }
  // B frag: B[k=quad*8+j][n=l15] from n-major Wt row (col), k-chunk quad*8
  const bf16_t* b_base[4];
#pragma unroll
  for (int bn = 0; bn < 4; ++bn) {
    int col = nblk * 128 + wn * 64 + bn * 16 + l15;
    b_base[bn] = Wt + ((size_t)t * 256 + col) * 1280 + quad * 8;
  }

  f32x4 acc[4][4];
#pragma unroll
  for (int i = 0; i < 4; ++i)
#pragma unroll
    for (int j = 0; j < 4; ++j) acc[i][j] = (f32x4){0.f, 0.f, 0.f, 0.f};

  bf16x8 af[2][4], bfv[2][4];

#define LOADF(buf, ks)                                                \
  {                                                                   \
    const int ko = (ks) * 32;                                         \
    _Pragma("unroll") for (int i = 0; i < 4; ++i) {                   \
      af[buf][i] = *(const bf16x8*)(a_base[i] + ko);                  \
      bfv[buf][i] = *(const bf16x8*)(b_base[i] + ko);                 \
    }                                                                 \
  }

#define MFMAS(buf)                                                             \
  {                                                                            \
    _Pragma("unroll") for (int am = 0; am < 4; ++am)                           \
        _Pragma("unroll") for (int bn = 0; bn < 4; ++bn)                       \
            acc[am][bn] = __builtin_amdgcn_mfma_f32_16x16x32_bf16(             \
                af[buf][am], bfv[buf][bn], acc[am][bn], 0, 0, 0);              \
  }

  LOADF(0, 0)
  LOADF(1, 1)
  for (int ks = 0; ks < 40; ks += 2) {
    MFMAS(0)                          // waits buf0; buf1's 8 loads stay in flight
    if (ks + 2 < 40) LOADF(0, ks + 2)
    MFMAS(1)                          // waits buf1; buf0's next 8 in flight
    if (ks + 3 < 40) LOADF(1, ks + 3)
  }
#undef LOADF
#undef MFMAS

  // Epilogue. C/D: col = l15 (n), row = quad*4 + reg (m).
  float wbv[4][6];
#pragma unroll
  for (int bn = 0; bn < 4; ++bn) {
    int col = nblk * 128 + wn * 64 + bn * 16 + l15;
    wbv[bn][0] = W_box[col];
    wbv[bn][1] = W_box[H_ + col];
    wbv[bn][2] = W_box[2 * H_ + col];
    wbv[bn][3] = W_box[3 * H_ + col];
    wbv[bn][4] = b_box[col];
    wbv[bn][5] = b_node[t * H_ + col];
  }
#pragma unroll
  for (int am = 0; am < 4; ++am) {
    int orow[4]; float4 bxv[4]; bool valid[4];
#pragma unroll
    for (int r = 0; r < 4; ++r) {
      int gidx = tile0 + wm * 64 + am * 16 + quad * 4 + r;
      valid[r] = (gidx < cnt);
      int ic = valid[r] ? gidx : (cnt - 1);
      int orw = rd[ic].x;
      orow[r] = orw;
      int b = orw / n_l;
      int i = orw - b * n_l;
      bxv[r] = *(const float4*)(ibox + ((size_t)b * NINT + off_l + i) * 4);
    }
#pragma unroll
    for (int bn = 0; bn < 4; ++bn) {
      int col = nblk * 128 + wn * 64 + bn * 16 + l15;
#pragma unroll
      for (int r = 0; r < 4; ++r) {
        if (!valid[r]) continue;
        float y = fmaxf(acc[am][bn][r] + wbv[bn][5], 0.f);
        float be = fmaf(wbv[bn][0], bxv[r].x,
                   fmaf(wbv[bn][1], bxv[r].y,
                   fmaf(wbv[bn][2], bxv[r].z,
                   fmaf(wbv[bn][3], bxv[r].w, wbv[bn][4]))));
        be = fmaxf(be, 0.f);
        dst[(size_t)orow[r] * H_ + col] = (bf16_t)(y + be);
      }
    }
  }
}

__global__ __launch_bounds__(256) void head_kernel(
    const bf16_t* __restrict__ f0, const float* __restrict__ eps,
    const float* __restrict__ W1, const float* __restrict__ b1,
    const float* __restrict__ Wmu, const float* __restrict__ bmu,
    const float* __restrict__ Wvar, const float* __restrict__ bvar,
    float* __restrict__ out) {
  __shared__ float root[256];
  __shared__ float enc[256];
  int b = blockIdx.x, h = threadIdx.x;
  root[h] = (float)f0[b * H_ + h];
  __syncthreads();
  float a = b1[h];
  for (int k = 0; k < 256; ++k) a = fmaf(root[k], W1[k * H_ + h], a);
  enc[h] = fmaxf(a, 0.f);
  __syncthreads();
  float m = bmu[h], lv = bvar[h];
  for (int k = 0; k < 256; ++k) {
    float e = enc[k];
    m = fmaf(e, Wmu[k * H_ + h], m);
    lv = fmaf(e, Wvar[k * H_ + h], lv);
  }
  float stdv = expf(0.5f * lv);
  float kld = 1.f + lv - m * m - expf(lv);
  out[b * 512 + h] = eps[b * H_ + h] * stdv + m;
  out[b * 512 + 256 + h] = kld;
}

extern "C" void kernel_launch(void* const* d_in, const int* in_sizes, int n_in,
                              void* d_out, int out_size, void* d_ws, size_t ws_size,
                              hipStream_t stream) {
  const float* leaf_box     = (const float*)d_in[0];
  const float* leaf_sem     = (const float*)d_in[1];
  const float* internal_box = (const float*)d_in[2];
  const int*   node_type    = (const int*)d_in[3];
  const float* eps          = (const float*)d_in[4];
  const float* W_box        = (const float*)d_in[5];
  const float* b_box        = (const float*)d_in[6];
  const float* W_sem        = (const float*)d_in[7];
  const float* b_sem        = (const float*)d_in[8];
  const float* W_node       = (const float*)d_in[9];
  const float* b_node       = (const float*)d_in[10];
  const float* W1           = (const float*)d_in[11];
  const float* b1           = (const float*)d_in[12];
  const float* Wmu          = (const float*)d_in[13];
  const float* bmu          = (const float*)d_in[14];
  const float* Wvar         = (const float*)d_in[15];
  const float* bvar         = (const float*)d_in[16];
  float* out = (float*)d_out;

  char* p = (char*)d_ws;
  auto alloc = [&](size_t bytes) {
    char* r = p;
    p += (bytes + 255) & ~(size_t)255;
    return r;
  };
  bf16_t* Wt = (bf16_t*)alloc((size_t)3 * 256 * 1280 * 2);
  const int n_tab[7] = {1, 5, 25, 125, 625, 3125, 15625};
  bf16_t* f[7];
  for (int l = 0; l <= 6; ++l) f[l] = (bf16_t*)alloc((size_t)B_ * n_tab[l] * H_ * 2);
  int* counters = (int*)alloc(18 * 4);
  int2* buckets = (int2*)alloc((size_t)187488 * 8);

  hipLaunchKernelGGL(prep_kernel, dim3(24), dim3(256), 0, stream, W_node, Wt, counters);
  hipLaunchKernelGGL(leaf_kernel, dim3(2048), dim3(256), 0, stream,
                     leaf_box, leaf_sem, W_box, b_box, W_sem, b_sem, f[6]);
  hipLaunchKernelGGL(bucket_kernel, dim3((B_ * NINT + 255) / 256), dim3(256), 0, stream,
                     node_type, counters, buckets);

  const int lvl_base[6] = {0, 48, 288, 1488, 7488, 37488};
  const int off_tab[6]  = {0, 1, 6, 31, 156, 781};
  for (int l = 5; l >= 0; --l) {
    int cap = B_ * n_tab[l];
    int tiles = (cap + 127) / 128;
    hipLaunchKernelGGL(level_kernel, dim3(tiles, 3, 2), dim3(256), 0, stream,
                       f[l + 1], f[l], buckets + lvl_base[l], counters + l * 3,
                       Wt, b_node, internal_box, W_box, b_box,
                       n_tab[l], off_tab[l], cap);
  }
  hipLaunchKernelGGL(head_kernel, dim3(16), dim3(256), 0, stream,
                     f[0], eps, W1, b1, Wmu, bmu, Wvar, bvar, out);
}

// Round 5
// 392.715 us; speedup vs baseline: 1.4935x; 1.4935x over previous
//
#include <hip/hip_runtime.h>

// RecursiveEncoder on MI355X. B=16, H=256, S=16, C=5, L=6, N_LEAF=15625, N_INT=3906.
// R5: revert R4's direct-global frags (regressed 85->168us). Level kernel = LDS-DMA
//     staging, BK=64 (20 stages, 128B A-segments for HBM efficiency), ONE barrier
//     per stage (ds_read frags -> issue prefetch DMA -> MFMA), 8-chunk XOR swizzle
//     (conflict-free). prep back to 240 blocks (24-block version was latency-bound).

#define B_ 16
#define H_ 256
#define NLEAF 15625
#define NINT 3906

typedef __bf16 bf16_t;
typedef bf16_t bf16x8 __attribute__((ext_vector_type(8)));
typedef bf16_t bf16x4 __attribute__((ext_vector_type(4)));
typedef float f32x4 __attribute__((ext_vector_type(4)));

__device__ __forceinline__ void gl2lds16(const bf16_t* g, bf16_t* l) {
  __builtin_amdgcn_global_load_lds((const __attribute__((address_space(1))) void*)g,
                                   (__attribute__((address_space(3))) void*)l,
                                   16, 0, 0);
}

// grid(240): t(3) x kc(80), 16 k each. Reads coalesced across lanes, 16B stores.
__global__ __launch_bounds__(256) void prep_kernel(const float* __restrict__ W_node,
                                                   bf16_t* __restrict__ Wt,
                                                   int* __restrict__ counters) {
  if (blockIdx.x == 0 && threadIdx.x < 18) counters[threadIdx.x] = 0;
  const int t = blockIdx.x / 80;
  const int kc = blockIdx.x % 80;
  const int h = threadIdx.x;
  const float* srcp = W_node + (size_t)t * 1280 * 256 + h;
  bf16_t* dstp = Wt + ((size_t)(t * 256 + h)) * 1280;
#pragma unroll
  for (int k0 = kc * 16; k0 < kc * 16 + 16; k0 += 8) {
    bf16x8 v;
#pragma unroll
    for (int j = 0; j < 8; ++j) v[j] = (bf16_t)srcp[(size_t)(k0 + j) * 256];
    *(bf16x8*)(dstp + k0) = v;
  }
}

// One row per wave, lane covers h = lane*4..lane*4+3; bf16x4 (8B) stores.
__global__ __launch_bounds__(256) void leaf_kernel(
    const float* __restrict__ leaf_box, const float* __restrict__ leaf_sem,
    const float* __restrict__ W_box, const float* __restrict__ b_box,
    const float* __restrict__ W_sem, const float* __restrict__ b_sem,
    bf16_t* __restrict__ f6) {
  const int lane = threadIdx.x & 63;
  const int wave = threadIdx.x >> 6;
  const int h0 = lane * 4;
  float wb[4][4], ws[16][4], bb[4], bs[4];
#pragma unroll
  for (int j = 0; j < 4; ++j) {
    float4 v = *(const float4*)(W_box + j * H_ + h0);
    wb[j][0] = v.x; wb[j][1] = v.y; wb[j][2] = v.z; wb[j][3] = v.w;
  }
#pragma unroll
  for (int j = 0; j < 16; ++j) {
    float4 v = *(const float4*)(W_sem + j * H_ + h0);
    ws[j][0] = v.x; ws[j][1] = v.y; ws[j][2] = v.z; ws[j][3] = v.w;
  }
  {
    float4 v = *(const float4*)(b_box + h0);
    bb[0] = v.x; bb[1] = v.y; bb[2] = v.z; bb[3] = v.w;
    float4 u = *(const float4*)(b_sem + h0);
    bs[0] = u.x; bs[1] = u.y; bs[2] = u.z; bs[3] = u.w;
  }
  const int ROWS = B_ * NLEAF;
  const int stride = gridDim.x * 4;
  for (int row = blockIdx.x * 4 + wave; row < ROWS; row += stride) {
    float4 bx = *(const float4*)(leaf_box + (size_t)row * 4);
    const float4* sp = (const float4*)(leaf_sem + (size_t)row * 16);
    float4 sv0 = sp[0], sv1 = sp[1], sv2 = sp[2], sv3 = sp[3];
    bf16x4 o;
#pragma unroll
    for (int c = 0; c < 4; ++c) {
      float s1 = fmaf(wb[0][c], bx.x, fmaf(wb[1][c], bx.y,
                 fmaf(wb[2][c], bx.z, fmaf(wb[3][c], bx.w, bb[c]))));
      float s2 = bs[c];
      s2 = fmaf(ws[0][c], sv0.x, s2);  s2 = fmaf(ws[1][c], sv0.y, s2);
      s2 = fmaf(ws[2][c], sv0.z, s2);  s2 = fmaf(ws[3][c], sv0.w, s2);
      s2 = fmaf(ws[4][c], sv1.x, s2);  s2 = fmaf(ws[5][c], sv1.y, s2);
      s2 = fmaf(ws[6][c], sv1.z, s2);  s2 = fmaf(ws[7][c], sv1.w, s2);
      s2 = fmaf(ws[8][c], sv2.x, s2);  s2 = fmaf(ws[9][c], sv2.y, s2);
      s2 = fmaf(ws[10][c], sv2.z, s2); s2 = fmaf(ws[11][c], sv2.w, s2);
      s2 = fmaf(ws[12][c], sv3.x, s2); s2 = fmaf(ws[13][c], sv3.y, s2);
      s2 = fmaf(ws[14][c], sv3.z, s2); s2 = fmaf(ws[15][c], sv3.w, s2);
      o[c] = (bf16_t)(fmaxf(s1, 0.f) + fmaxf(s2, 0.f));
    }
    *(bf16x4*)(f6 + (size_t)row * H_ + h0) = o;
  }
}

// LDS-aggregated bucketing (block-local order preserved -> decent A locality).
__global__ __launch_bounds__(256) void bucket_kernel(const int* __restrict__ node_type,
                                                     int* __restrict__ counters,
                                                     int2* __restrict__ buckets) {
  __shared__ int lcnt[18];
  __shared__ int lbase[18];
  const int tid = threadIdx.x;
  if (tid < 18) lcnt[tid] = 0;
  __syncthreads();

  int idx = blockIdx.x * 256 + tid;
  bool active = idx < B_ * NINT;
  int t = 0, key = 0, mypos = 0;
  int2 e;
  int base = 0, nl_cap = 0;
  if (active) {
    int b = idx / NINT;
    int j = idx - b * NINT;
    int l, off;
    if (j >= 781)      { l = 5; off = 781; }
    else if (j >= 156) { l = 4; off = 156; }
    else if (j >= 31)  { l = 3; off = 31; }
    else if (j >= 6)   { l = 2; off = 6; }
    else if (j >= 1)   { l = 1; off = 1; }
    else               { l = 0; off = 0; }
    const int n_tab[6]    = {1, 5, 25, 125, 625, 3125};
    const int nn_tab[6]   = {5, 25, 125, 625, 3125, 15625};
    const int base_tab[6] = {0, 48, 288, 1488, 7488, 37488};
    int n_l = n_tab[l], nn = nn_tab[l];
    t = node_type[idx];
    int i = j - off;
    e.x = b * n_l + i;
    e.y = b * nn + 5 * i;
    base = base_tab[l];
    nl_cap = B_ * n_l;
    key = l * 3 + t;
    mypos = atomicAdd(&lcnt[key], 1);
  }
  __syncthreads();
  if (tid < 18) {
    int c = lcnt[tid];
    lbase[tid] = c ? atomicAdd(&counters[tid], c) : 0;
  }
  __syncthreads();
  if (active) {
    buckets[base + t * nl_cap + lbase[key] + mypos] = e;
  }
}

// 128x128 tile, K=1280 in 20 stages of 64, double-buffered lds-DMA, one barrier
// per stage: sync -> ds_read frags -> issue next-stage DMA (overlaps MFMAs) -> MFMA.
__global__ __launch_bounds__(256) void level_kernel(
    const bf16_t* __restrict__ src, bf16_t* __restrict__ dst,
    const int2* __restrict__ bucket, const int* __restrict__ counters,
    const bf16_t* __restrict__ Wt, const float* __restrict__ b_node,
    const float* __restrict__ ibox, const float* __restrict__ W_box,
    const float* __restrict__ b_box, int n_l, int off_l, int cap) {
  const int t = blockIdx.y;
  const int cnt = counters[t];
  const int tile0 = blockIdx.x * 128;
  if (tile0 >= cnt) return;
  const int nblk = blockIdx.z;
  const int2* rd = bucket + (size_t)t * cap;

  __shared__ __align__(16) bf16_t Asm[2][128][64];  // 16 KB per buf
  __shared__ __align__(16) bf16_t Bsm[2][128][64];

  const int tid = threadIdx.x;
  const int lane = tid & 63;
  const int wave = tid >> 6;
  const int wm = wave & 1, wn = wave >> 1;
  const int quad = lane >> 4;
  const int l15 = lane & 15;

  // staging: per issue i, thread covers row r = 32*i + (tid>>3), LDS chunk tid&7,
  // holding GLOBAL chunk (tid&7) ^ ((r>>1)&7).  LDS slot elem = 2048*i + tid*8.
  const int r8 = tid >> 3;
  const int sc = tid & 7;
  const bf16_t* wsrc = Wt + ((size_t)t * 256 + nblk * 128) * 1280;
  const bf16_t* aptr[4];
  const bf16_t* bptr[4];
#pragma unroll
  for (int i = 0; i < 4; ++i) {
    int r = i * 32 + r8;
    int gch = sc ^ ((r >> 1) & 7);
    int ai = tile0 + r;
    if (ai >= cnt) ai = cnt - 1;
    aptr[i] = src + (size_t)rd[ai].y * H_ + gch * 8;
    bptr[i] = wsrc + (size_t)r * 1280 + gch * 8;
  }

  f32x4 acc[4][4];
#pragma unroll
  for (int i = 0; i < 4; ++i)
#pragma unroll
    for (int j = 0; j < 4; ++j) acc[i][j] = (f32x4){0.f, 0.f, 0.f, 0.f};

  // frag read: logical chunk (kk*4+quad), physical = logical ^ ((l15>>1)&7)
  const int sw = (l15 >> 1) & 7;
  const int pc0 = ((0 * 4 + quad) ^ sw) * 8;
  const int pc1 = ((1 * 4 + quad) ^ sw) * 8;

#define STAGE(buf, ks)                                          \
  {                                                             \
    const int ko = (ks) * 64;                                   \
    bf16_t* la = &Asm[buf][0][0] + wave * 512;                  \
    bf16_t* lb = &Bsm[buf][0][0] + wave * 512;                  \
    _Pragma("unroll") for (int i = 0; i < 4; ++i)               \
        gl2lds16(aptr[i] + ko, la + i * 2048);                  \
    _Pragma("unroll") for (int i = 0; i < 4; ++i)               \
        gl2lds16(bptr[i] + ko, lb + i * 2048);                  \
  }

  STAGE(0, 0)
  for (int ks = 0; ks < 20; ++ks) {
    const int buf = ks & 1;
    __syncthreads();  // drains DMA for stage ks; prior-buf readers all done
    bf16x8 af0[4], af1[4], bf0[4], bf1[4];
#pragma unroll
    for (int am = 0; am < 4; ++am) {
      af0[am] = *(const bf16x8*)(&Asm[buf][wm * 64 + am * 16 + l15][pc0]);
      af1[am] = *(const bf16x8*)(&Asm[buf][wm * 64 + am * 16 + l15][pc1]);
    }
#pragma unroll
    for (int bn = 0; bn < 4; ++bn) {
      bf0[bn] = *(const bf16x8*)(&Bsm[buf][wn * 64 + bn * 16 + l15][pc0]);
      bf1[bn] = *(const bf16x8*)(&Bsm[buf][wn * 64 + bn * 16 + l15][pc1]);
    }
    if (ks + 1 < 20) STAGE(buf ^ 1, ks + 1)  // prefetch overlaps the 32 MFMAs
#pragma unroll
    for (int am = 0; am < 4; ++am)
#pragma unroll
      for (int bn = 0; bn < 4; ++bn)
        acc[am][bn] = __builtin_amdgcn_mfma_f32_16x16x32_bf16(af0[am], bf0[bn], acc[am][bn], 0, 0, 0);
#pragma unroll
    for (int am = 0; am < 4; ++am)
#pragma unroll
      for (int bn = 0; bn < 4; ++bn)
        acc[am][bn] = __builtin_amdgcn_mfma_f32_16x16x32_bf16(af1[am], bf1[bn], acc[am][bn], 0, 0, 0);
  }
#undef STAGE

  // Epilogue. C/D: col = l15 (n), row = quad*4 + reg (m).
  float wbv[4][6];
#pragma unroll
  for (int bn = 0; bn < 4; ++bn) {
    int col = nblk * 128 + wn * 64 + bn * 16 + l15;
    wbv[bn][0] = W_box[col];
    wbv[bn][1] = W_box[H_ + col];
    wbv[bn][2] = W_box[2 * H_ + col];
    wbv[bn][3] = W_box[3 * H_ + col];
    wbv[bn][4] = b_box[col];
    wbv[bn][5] = b_node[t * H_ + col];
  }
#pragma unroll
  for (int am = 0; am < 4; ++am) {
    int orow[4]; float4 bxv[4]; bool valid[4];
#pragma unroll
    for (int r = 0; r < 4; ++r) {
      int gidx = tile0 + wm * 64 + am * 16 + quad * 4 + r;
      valid[r] = (gidx < cnt);
      int ic = valid[r] ? gidx : (cnt - 1);
      int orw = rd[ic].x;
      orow[r] = orw;
      int b = orw / n_l;
      int i = orw - b * n_l;
      bxv[r] = *(const float4*)(ibox + ((size_t)b * NINT + off_l + i) * 4);
    }
#pragma unroll
    for (int bn = 0; bn < 4; ++bn) {
      int col = nblk * 128 + wn * 64 + bn * 16 + l15;
#pragma unroll
      for (int r = 0; r < 4; ++r) {
        if (!valid[r]) continue;
        float y = fmaxf(acc[am][bn][r] + wbv[bn][5], 0.f);
        float be = fmaf(wbv[bn][0], bxv[r].x,
                   fmaf(wbv[bn][1], bxv[r].y,
                   fmaf(wbv[bn][2], bxv[r].z,
                   fmaf(wbv[bn][3], bxv[r].w, wbv[bn][4]))));
        be = fmaxf(be, 0.f);
        dst[(size_t)orow[r] * H_ + col] = (bf16_t)(y + be);
      }
    }
  }
}

__global__ __launch_bounds__(256) void head_kernel(
    const bf16_t* __restrict__ f0, const float* __restrict__ eps,
    const float* __restrict__ W1, const float* __restrict__ b1,
    const float* __restrict__ Wmu, const float* __restrict__ bmu,
    const float* __restrict__ Wvar, const float* __restrict__ bvar,
    float* __restrict__ out) {
  __shared__ float root[256];
  __shared__ float enc[256];
  int b = blockIdx.x, h = threadIdx.x;
  root[h] = (float)f0[b * H_ + h];
  __syncthreads();
  float a = b1[h];
  for (int k = 0; k < 256; ++k) a = fmaf(root[k], W1[k * H_ + h], a);
  enc[h] = fmaxf(a, 0.f);
  __syncthreads();
  float m = bmu[h], lv = bvar[h];
  for (int k = 0; k < 256; ++k) {
    float e = enc[k];
    m = fmaf(e, Wmu[k * H_ + h], m);
    lv = fmaf(e, Wvar[k * H_ + h], lv);
  }
  float stdv = expf(0.5f * lv);
  float kld = 1.f + lv - m * m - expf(lv);
  out[b * 512 + h] = eps[b * H_ + h] * stdv + m;
  out[b * 512 + 256 + h] = kld;
}

extern "C" void kernel_launch(void* const* d_in, const int* in_sizes, int n_in,
                              void* d_out, int out_size, void* d_ws, size_t ws_size,
                              hipStream_t stream) {
  const float* leaf_box     = (const float*)d_in[0];
  const float* leaf_sem     = (const float*)d_in[1];
  const float* internal_box = (const float*)d_in[2];
  const int*   node_type    = (const int*)d_in[3];
  const float* eps          = (const float*)d_in[4];
  const float* W_box        = (const float*)d_in[5];
  const float* b_box        = (const float*)d_in[6];
  const float* W_sem        = (const float*)d_in[7];
  const float* b_sem        = (const float*)d_in[8];
  const float* W_node       = (const float*)d_in[9];
  const float* b_node       = (const float*)d_in[10];
  const float* W1           = (const float*)d_in[11];
  const float* b1           = (const float*)d_in[12];
  const float* Wmu          = (const float*)d_in[13];
  const float* bmu          = (const float*)d_in[14];
  const float* Wvar         = (const float*)d_in[15];
  const float* bvar         = (const float*)d_in[16];
  float* out = (float*)d_out;

  char* p = (char*)d_ws;
  auto alloc = [&](size_t bytes) {
    char* r = p;
    p += (bytes + 255) & ~(size_t)255;
    return r;
  };
  bf16_t* Wt = (bf16_t*)alloc((size_t)3 * 256 * 1280 * 2);
  const int n_tab[7] = {1, 5, 25, 125, 625, 3125, 15625};
  bf16_t* f[7];
  for (int l = 0; l <= 6; ++l) f[l] = (bf16_t*)alloc((size_t)B_ * n_tab[l] * H_ * 2);
  int* counters = (int*)alloc(18 * 4);
  int2* buckets = (int2*)alloc((size_t)187488 * 8);

  hipLaunchKernelGGL(prep_kernel, dim3(240), dim3(256), 0, stream, W_node, Wt, counters);
  hipLaunchKernelGGL(leaf_kernel, dim3(2048), dim3(256), 0, stream,
                     leaf_box, leaf_sem, W_box, b_box, W_sem, b_sem, f[6]);
  hipLaunchKernelGGL(bucket_kernel, dim3((B_ * NINT + 255) / 256), dim3(256), 0, stream,
                     node_type, counters, buckets);

  const int lvl_base[6] = {0, 48, 288, 1488, 7488, 37488};
  const int off_tab[6]  = {0, 1, 6, 31, 156, 781};
  for (int l = 5; l >= 0; --l) {
    int cap = B_ * n_tab[l];
    int tiles = (cap + 127) / 128;
    hipLaunchKernelGGL(level_kernel, dim3(tiles, 3, 2), dim3(256), 0, stream,
                       f[l + 1], f[l], buckets + lvl_base[l], counters + l * 3,
                       Wt, b_node, internal_box, W_box, b_box,
                       n_tab[l], off_tab[l], cap);
  }
  hipLaunchKernelGGL(head_kernel, dim3(16), dim3(256), 0, stream,
                     f[0], eps, W1, b1, Wmu, bmu, Wvar, bvar, out);
}